// Round 1
// baseline (1777.614 us; speedup 1.0000x reference)
//
#include <hip/hip_runtime.h>

// APPNP power iteration: l <- alpha*init + (1-alpha) * A_hat @ l, 5 rounds.
// Edge-list SpMM via scatter-atomics; d_out doubles as the "current l" buffer.

constexpr float ALPHA = 0.15f;
constexpr int   NPROP = 5;
constexpr int   NCLASS = 50;

__global__ void zero_kernel(float* __restrict__ p, int n) {
    int i = blockIdx.x * blockDim.x + threadIdx.x;
    int stride = gridDim.x * blockDim.x;
    for (; i < n; i += stride) p[i] = 0.0f;
}

// 64 lanes per edge; lanes 0..49 each handle one class. Gather l[src*50+c],
// scale by val, atomicAdd into agg[dst*50+c]. Both accesses are contiguous
// 50-float runs -> coalesced within the lane group.
__global__ __launch_bounds__(256) void scatter_kernel(
    const float* __restrict__ l,
    const int*   __restrict__ rows,
    const int*   __restrict__ cols,
    const float* __restrict__ vals,
    float*       __restrict__ agg,
    int E) {
    long long gid = (long long)blockIdx.x * blockDim.x + threadIdx.x;
    int e = (int)(gid >> 6);
    if (e >= E) return;
    int c = (int)(gid & 63);
    if (c >= NCLASS) return;
    float v  = vals[e];
    int src  = cols[e];
    int dst  = rows[e];
    float m  = v * l[(long long)src * NCLASS + c];
    atomicAdd(&agg[(long long)dst * NCLASS + c], m);
}

__global__ void combine_kernel(const float* __restrict__ init,
                               const float* __restrict__ agg,
                               float*       __restrict__ out,
                               int n) {
    int i = blockIdx.x * blockDim.x + threadIdx.x;
    int stride = gridDim.x * blockDim.x;
    for (; i < n; i += stride)
        out[i] = ALPHA * init[i] + (1.0f - ALPHA) * agg[i];
}

extern "C" void kernel_launch(void* const* d_in, const int* in_sizes, int n_in,
                              void* d_out, int out_size, void* d_ws, size_t ws_size,
                              hipStream_t stream) {
    const float* logits = (const float*)d_in[0];
    const int*   rows   = (const int*)d_in[1];
    const int*   cols   = (const int*)d_in[2];
    const float* vals   = (const float*)d_in[3];
    float* out = (float*)d_out;
    float* agg = (float*)d_ws;            // N*C floats = 20 MB scratch

    const int E  = in_sizes[1];           // 1.6M edges
    const int NC = out_size;              // N*C = 5M

    long long sthreads = (long long)E * 64;
    int sblocks = (int)((sthreads + 255) / 256);
    int cblocks = (NC + 255) / 256;

    const float* cur = logits;
    for (int it = 0; it < NPROP; ++it) {
        zero_kernel<<<2048, 256, 0, stream>>>(agg, NC);
        scatter_kernel<<<sblocks, 256, 0, stream>>>(cur, rows, cols, vals, agg, E);
        combine_kernel<<<cblocks, 256, 0, stream>>>(logits, agg, out, NC);
        cur = out;  // d_out is the l-buffer for subsequent iterations
    }
}

// Round 2
// 845.993 us; speedup vs baseline: 2.1012x; 2.1012x over previous
//
#include <hip/hip_runtime.h>

// APPNP power iteration: l <- alpha*init + (1-alpha) * A_hat @ l, 5 rounds.
// Round 2: build dst-grouped CSR once per launch, then 5x pull-mode fused
// SpMM+combine (no atomics in the hot loop). Ping-pong l between d_out and ws.

constexpr float ALPHA  = 0.15f;
constexpr int   NPROP  = 5;
constexpr int   NCLASS = 50;
constexpr int   C2     = 25;   // float2 lanes per node row (50 floats)
constexpr int   NPB    = 10;   // nodes per 256-thread block (250 active)

// ---------------- CSR build ----------------

__global__ void zero_i32(int* __restrict__ p, int n) {
    int i = blockIdx.x * blockDim.x + threadIdx.x;
    int stride = gridDim.x * blockDim.x;
    for (; i < n; i += stride) p[i] = 0;
}

__global__ void hist_kernel(const int* __restrict__ rows, int* __restrict__ counts, int E) {
    int i = blockIdx.x * blockDim.x + threadIdx.x;
    int stride = gridDim.x * blockDim.x;
    for (; i < E; i += stride) atomicAdd(&counts[rows[i]], 1);
}

// Single-block chunked exclusive scan: counts[0..n) -> offsets in place,
// also mirrored into cursor[]; offsets[n] = E.
__global__ __launch_bounds__(1024) void scan_kernel(int* __restrict__ counts,
                                                    int* __restrict__ cursor,
                                                    int n, int E) {
    __shared__ int sums[1024];
    int t = threadIdx.x;
    int chunk = (n + 1023) / 1024;
    int lo = t * chunk;
    int hi = lo + chunk; if (hi > n) hi = n; if (lo > n) lo = n;
    int s = 0;
    for (int i = lo; i < hi; ++i) s += counts[i];
    sums[t] = s;
    __syncthreads();
    for (int off = 1; off < 1024; off <<= 1) {
        int v = (t >= off) ? sums[t - off] : 0;
        __syncthreads();
        sums[t] += v;
        __syncthreads();
    }
    int run = (t == 0) ? 0 : sums[t - 1];
    for (int i = lo; i < hi; ++i) {
        int v = counts[i];
        counts[i] = run;
        cursor[i] = run;
        run += v;
    }
    if (t == 0) counts[n] = E;
}

__global__ void fill_kernel(const int* __restrict__ rows, const int* __restrict__ cols,
                            const float* __restrict__ vals, int* __restrict__ cursor,
                            int* __restrict__ ccol, float* __restrict__ cval, int E) {
    int i = blockIdx.x * blockDim.x + threadIdx.x;
    int stride = gridDim.x * blockDim.x;
    for (; i < E; i += stride) {
        int r = rows[i];
        int p = atomicAdd(&cursor[r], 1);
        ccol[p] = cols[i];
        cval[p] = vals[i];
    }
}

// ---------------- Fused pull SpMM + combine ----------------
// 25 threads per node, one float2 (2 classes) each.

__global__ __launch_bounds__(256) void spmm_kernel(
    const float* __restrict__ l, const float* __restrict__ init,
    const int* __restrict__ offs, const int* __restrict__ ccol,
    const float* __restrict__ cval, float* __restrict__ out, int n) {
    int t = threadIdx.x;
    if (t >= NPB * C2) return;
    int node = blockIdx.x * NPB + t / C2;
    if (node >= n) return;
    int c = t % C2;
    int beg = offs[node], end = offs[node + 1];
    float ax = 0.f, ay = 0.f;
    const float2* l2 = (const float2*)l;
    for (int k = beg; k < end; ++k) {
        int src = ccol[k];
        float v = cval[k];
        float2 lv = l2[src * C2 + c];
        ax = fmaf(v, lv.x, ax);
        ay = fmaf(v, lv.y, ay);
    }
    float2 iv = ((const float2*)init)[node * C2 + c];
    float2 o;
    o.x = ALPHA * iv.x + (1.0f - ALPHA) * ax;
    o.y = ALPHA * iv.y + (1.0f - ALPHA) * ay;
    ((float2*)out)[node * C2 + c] = o;
}

// ---------------- Fallback (round-1 atomic path) ----------------

__global__ void zero_f32(float* __restrict__ p, int n) {
    int i = blockIdx.x * blockDim.x + threadIdx.x;
    int stride = gridDim.x * blockDim.x;
    for (; i < n; i += stride) p[i] = 0.0f;
}

__global__ __launch_bounds__(256) void scatter_kernel(
    const float* __restrict__ l, const int* __restrict__ rows,
    const int* __restrict__ cols, const float* __restrict__ vals,
    float* __restrict__ agg, int E) {
    long long gid = (long long)blockIdx.x * blockDim.x + threadIdx.x;
    int e = (int)(gid >> 6);
    if (e >= E) return;
    int c = (int)(gid & 63);
    if (c >= NCLASS) return;
    float m = vals[e] * l[(long long)cols[e] * NCLASS + c];
    atomicAdd(&agg[(long long)rows[e] * NCLASS + c], m);
}

__global__ void combine_kernel(const float* __restrict__ init,
                               const float* __restrict__ agg,
                               float* __restrict__ out, int n) {
    int i = blockIdx.x * blockDim.x + threadIdx.x;
    int stride = gridDim.x * blockDim.x;
    for (; i < n; i += stride)
        out[i] = ALPHA * init[i] + (1.0f - ALPHA) * agg[i];
}

// ---------------- Launch ----------------

static inline size_t align_up(size_t x, size_t a) { return (x + a - 1) & ~(a - 1); }

extern "C" void kernel_launch(void* const* d_in, const int* in_sizes, int n_in,
                              void* d_out, int out_size, void* d_ws, size_t ws_size,
                              hipStream_t stream) {
    const float* logits = (const float*)d_in[0];
    const int*   rows   = (const int*)d_in[1];
    const int*   cols   = (const int*)d_in[2];
    const float* vals   = (const float*)d_in[3];
    float* out = (float*)d_out;

    const int E  = in_sizes[1];
    const int NC = out_size;
    const int N  = NC / NCLASS;

    // ws layout for CSR path
    size_t off_offs   = 0;
    size_t off_cursor = align_up(off_offs   + (size_t)(N + 1) * 4, 256);
    size_t off_ccol   = align_up(off_cursor + (size_t)N * 4,       256);
    size_t off_cval   = align_up(off_ccol   + (size_t)E * 4,       256);
    size_t off_lbuf   = align_up(off_cval   + (size_t)E * 4,       256);
    size_t need       = off_lbuf + (size_t)NC * 4;

    if (ws_size >= need) {
        char* ws = (char*)d_ws;
        int*   offs   = (int*)  (ws + off_offs);
        int*   cursor = (int*)  (ws + off_cursor);
        int*   ccol   = (int*)  (ws + off_ccol);
        float* cval   = (float*)(ws + off_cval);
        float* lbuf   = (float*)(ws + off_lbuf);

        int eblocks = (E + 255) / 256; if (eblocks > 2048) eblocks = 2048;
        zero_i32<<<(N + 1 + 255) / 256, 256, 0, stream>>>(offs, N + 1);
        hist_kernel<<<eblocks, 256, 0, stream>>>(rows, offs, E);
        scan_kernel<<<1, 1024, 0, stream>>>(offs, cursor, N, E);
        fill_kernel<<<eblocks, 256, 0, stream>>>(rows, cols, vals, cursor, ccol, cval, E);

        int sblocks = (N + NPB - 1) / NPB;
        // ping-pong: it0 logits->out, it1 out->lbuf, it2 lbuf->out,
        //            it3 out->lbuf, it4 lbuf->out   (NPROP=5, final in d_out)
        const float* cur = logits;
        float* dst = out;
        for (int it = 0; it < NPROP; ++it) {
            spmm_kernel<<<sblocks, 256, 0, stream>>>(cur, logits, offs, ccol, cval, dst, N);
            cur = dst;
            dst = (dst == out) ? lbuf : out;
        }
        // NPROP odd -> last write was to `out` iff NPROP is odd. it indices:
        // writes go out,lbuf,out,lbuf,out -> final in d_out. Correct.
    } else {
        // Fallback: atomic scatter path (needs only NC floats of ws)
        float* agg = (float*)d_ws;
        long long sthreads = (long long)E * 64;
        int sblocks = (int)((sthreads + 255) / 256);
        int cblocks = (NC + 255) / 256;
        const float* cur = logits;
        for (int it = 0; it < NPROP; ++it) {
            zero_f32<<<2048, 256, 0, stream>>>(agg, NC);
            scatter_kernel<<<sblocks, 256, 0, stream>>>(cur, rows, cols, vals, agg, E);
            combine_kernel<<<cblocks, 256, 0, stream>>>(logits, agg, out, NC);
            cur = out;
        }
    }
}

// Round 3
// 621.344 us; speedup vs baseline: 2.8609x; 1.3616x over previous
//
#include <hip/hip_runtime.h>

// APPNP power iteration: l <- alpha*init + (1-alpha) * A_hat @ l, 5 rounds.
// Round 3: multi-block two-level scan for the CSR build (round-2's single-block
// scan was 227 us on one CU). Pull-mode fused SpMM+combine unchanged.

constexpr float ALPHA  = 0.15f;
constexpr int   NPROP  = 5;
constexpr int   NCLASS = 50;
constexpr int   C2     = 25;   // float2 lanes per node row (50 floats)
constexpr int   NPB    = 10;   // nodes per 256-thread block (250 active)
constexpr int   SCAN_BLOCKS = 256;

// ---------------- CSR build ----------------

__global__ void zero_i32(int* __restrict__ p, int n) {
    int i = blockIdx.x * blockDim.x + threadIdx.x;
    int stride = gridDim.x * blockDim.x;
    for (; i < n; i += stride) p[i] = 0;
}

__global__ void hist_kernel(const int* __restrict__ rows, int* __restrict__ counts, int E) {
    int i = blockIdx.x * blockDim.x + threadIdx.x;
    int stride = gridDim.x * blockDim.x;
    for (; i < E; i += stride) atomicAdd(&counts[rows[i]], 1);
}

// k1: per-block chunk sums
__global__ __launch_bounds__(256) void reduce_chunk(const int* __restrict__ counts,
                                                    int* __restrict__ bs, int n) {
    __shared__ int tsum[256];
    int b = blockIdx.x, t = threadIdx.x;
    int chunk = (n + gridDim.x - 1) / gridDim.x;
    int blo = b * chunk;
    int bhi = blo + chunk; if (bhi > n) bhi = n;
    int s = 0;
    for (int i = blo + t; i < bhi; i += 256) s += counts[i];
    tsum[t] = s;
    __syncthreads();
    for (int off = 128; off; off >>= 1) {
        if (t < off) tsum[t] += tsum[t + off];
        __syncthreads();
    }
    if (t == 0) bs[b] = tsum[0];
}

// k2: exclusive scan of the 256 block sums (single tiny block)
__global__ __launch_bounds__(256) void scan_blocksums(int* __restrict__ bs) {
    __shared__ int tmp[256];
    int t = threadIdx.x;
    tmp[t] = bs[t];
    __syncthreads();
    for (int off = 1; off < 256; off <<= 1) {
        int v = (t >= off) ? tmp[t - off] : 0;
        __syncthreads();
        tmp[t] += v;
        __syncthreads();
    }
    bs[t] = t ? tmp[t - 1] : 0;
}

// k3: per-chunk exclusive prefix with block base -> offs, cursor
__global__ __launch_bounds__(256) void scan_chunk(const int* __restrict__ counts,
                                                  const int* __restrict__ bs,
                                                  int* __restrict__ offs,
                                                  int* __restrict__ cursor,
                                                  int n, int E) {
    __shared__ int tsum[256];
    int b = blockIdx.x, t = threadIdx.x;
    int chunk = (n + gridDim.x - 1) / gridDim.x;
    int blo = b * chunk;
    int bhi = blo + chunk; if (bhi > n) bhi = n;
    int per = (chunk + 255) / 256;
    int lo = blo + t * per;
    int hi = lo + per;
    if (lo > bhi) lo = bhi;
    if (hi > bhi) hi = bhi;
    int s = 0;
    for (int i = lo; i < hi; ++i) s += counts[i];
    tsum[t] = s;
    __syncthreads();
    for (int off = 1; off < 256; off <<= 1) {
        int v = (t >= off) ? tsum[t - off] : 0;
        __syncthreads();
        tsum[t] += v;
        __syncthreads();
    }
    int run = bs[b] + (t ? tsum[t - 1] : 0);
    for (int i = lo; i < hi; ++i) {
        int v = counts[i];
        offs[i] = run;
        cursor[i] = run;
        run += v;
    }
    if (b == 0 && t == 0) offs[n] = E;
}

__global__ void fill_kernel(const int* __restrict__ rows, const int* __restrict__ cols,
                            const float* __restrict__ vals, int* __restrict__ cursor,
                            int* __restrict__ ccol, float* __restrict__ cval, int E) {
    int i = blockIdx.x * blockDim.x + threadIdx.x;
    int stride = gridDim.x * blockDim.x;
    for (; i < E; i += stride) {
        int r = rows[i];
        int p = atomicAdd(&cursor[r], 1);
        ccol[p] = cols[i];
        cval[p] = vals[i];
    }
}

// ---------------- Fused pull SpMM + combine ----------------

__global__ __launch_bounds__(256) void spmm_kernel(
    const float* __restrict__ l, const float* __restrict__ init,
    const int* __restrict__ offs, const int* __restrict__ ccol,
    const float* __restrict__ cval, float* __restrict__ out, int n) {
    int t = threadIdx.x;
    if (t >= NPB * C2) return;
    int node = blockIdx.x * NPB + t / C2;
    if (node >= n) return;
    int c = t % C2;
    int beg = offs[node], end = offs[node + 1];
    float ax = 0.f, ay = 0.f;
    const float2* l2 = (const float2*)l;
    for (int k = beg; k < end; ++k) {
        int src = ccol[k];
        float v = cval[k];
        float2 lv = l2[src * C2 + c];
        ax = fmaf(v, lv.x, ax);
        ay = fmaf(v, lv.y, ay);
    }
    float2 iv = ((const float2*)init)[node * C2 + c];
    float2 o;
    o.x = ALPHA * iv.x + (1.0f - ALPHA) * ax;
    o.y = ALPHA * iv.y + (1.0f - ALPHA) * ay;
    ((float2*)out)[node * C2 + c] = o;
}

// ---------------- Fallback (atomic path) ----------------

__global__ void zero_f32(float* __restrict__ p, int n) {
    int i = blockIdx.x * blockDim.x + threadIdx.x;
    int stride = gridDim.x * blockDim.x;
    for (; i < n; i += stride) p[i] = 0.0f;
}

__global__ __launch_bounds__(256) void scatter_kernel(
    const float* __restrict__ l, const int* __restrict__ rows,
    const int* __restrict__ cols, const float* __restrict__ vals,
    float* __restrict__ agg, int E) {
    long long gid = (long long)blockIdx.x * blockDim.x + threadIdx.x;
    int e = (int)(gid >> 6);
    if (e >= E) return;
    int c = (int)(gid & 63);
    if (c >= NCLASS) return;
    float m = vals[e] * l[(long long)cols[e] * NCLASS + c];
    atomicAdd(&agg[(long long)rows[e] * NCLASS + c], m);
}

__global__ void combine_kernel(const float* __restrict__ init,
                               const float* __restrict__ agg,
                               float* __restrict__ out, int n) {
    int i = blockIdx.x * blockDim.x + threadIdx.x;
    int stride = gridDim.x * blockDim.x;
    for (; i < n; i += stride)
        out[i] = ALPHA * init[i] + (1.0f - ALPHA) * agg[i];
}

// ---------------- Launch ----------------

static inline size_t align_up(size_t x, size_t a) { return (x + a - 1) & ~(a - 1); }

extern "C" void kernel_launch(void* const* d_in, const int* in_sizes, int n_in,
                              void* d_out, int out_size, void* d_ws, size_t ws_size,
                              hipStream_t stream) {
    const float* logits = (const float*)d_in[0];
    const int*   rows   = (const int*)d_in[1];
    const int*   cols   = (const int*)d_in[2];
    const float* vals   = (const float*)d_in[3];
    float* out = (float*)d_out;

    const int E  = in_sizes[1];
    const int NC = out_size;
    const int N  = NC / NCLASS;

    // ws layout for CSR path
    size_t off_counts = 0;
    size_t off_offs   = align_up(off_counts + (size_t)N * 4,        256);
    size_t off_cursor = align_up(off_offs   + (size_t)(N + 1) * 4,  256);
    size_t off_bs     = align_up(off_cursor + (size_t)N * 4,        256);
    size_t off_ccol   = align_up(off_bs     + (size_t)SCAN_BLOCKS * 4, 256);
    size_t off_cval   = align_up(off_ccol   + (size_t)E * 4,        256);
    size_t off_lbuf   = align_up(off_cval   + (size_t)E * 4,        256);
    size_t need       = off_lbuf + (size_t)NC * 4;

    if (ws_size >= need) {
        char* ws = (char*)d_ws;
        int*   counts = (int*)  (ws + off_counts);
        int*   offs   = (int*)  (ws + off_offs);
        int*   cursor = (int*)  (ws + off_cursor);
        int*   bs     = (int*)  (ws + off_bs);
        int*   ccol   = (int*)  (ws + off_ccol);
        float* cval   = (float*)(ws + off_cval);
        float* lbuf   = (float*)(ws + off_lbuf);

        int eblocks = (E + 255) / 256; if (eblocks > 2048) eblocks = 2048;
        zero_i32<<<(N + 255) / 256, 256, 0, stream>>>(counts, N);
        hist_kernel<<<eblocks, 256, 0, stream>>>(rows, counts, E);
        reduce_chunk<<<SCAN_BLOCKS, 256, 0, stream>>>(counts, bs, N);
        scan_blocksums<<<1, 256, 0, stream>>>(bs);
        scan_chunk<<<SCAN_BLOCKS, 256, 0, stream>>>(counts, bs, offs, cursor, N, E);
        fill_kernel<<<eblocks, 256, 0, stream>>>(rows, cols, vals, cursor, ccol, cval, E);

        int sblocks = (N + NPB - 1) / NPB;
        // ping-pong writes: out,lbuf,out,lbuf,out -> final result in d_out
        const float* cur = logits;
        float* dst = out;
        for (int it = 0; it < NPROP; ++it) {
            spmm_kernel<<<sblocks, 256, 0, stream>>>(cur, logits, offs, ccol, cval, dst, N);
            cur = dst;
            dst = (dst == out) ? lbuf : out;
        }
    } else {
        // Fallback: atomic scatter path (needs only NC floats of ws)
        float* agg = (float*)d_ws;
        long long sthreads = (long long)E * 64;
        int sblocks = (int)((sthreads + 255) / 256);
        int cblocks = (NC + 255) / 256;
        const float* cur = logits;
        for (int it = 0; it < NPROP; ++it) {
            zero_f32<<<2048, 256, 0, stream>>>(agg, NC);
            scatter_kernel<<<sblocks, 256, 0, stream>>>(cur, rows, cols, vals, agg, E);
            combine_kernel<<<cblocks, 256, 0, stream>>>(logits, agg, out, NC);
            cur = out;
        }
    }
}